// Round 6
// baseline (362.036 us; speedup 1.0000x reference)
//
#include <hip/hip_runtime.h>
#include <stdint.h>

typedef _Float16 f16;
typedef _Float16 f16x8 __attribute__((ext_vector_type(8)));
typedef _Float16 f16x4 __attribute__((ext_vector_type(4)));
typedef _Float16 f16x2 __attribute__((ext_vector_type(2)));
typedef float f32x4 __attribute__((ext_vector_type(4)));

__device__ __forceinline__ f32x4 mfma16(f16x8 a, f16x8 b, f32x4 c) {
    return __builtin_amdgcn_mfma_f32_16x16x32_f16(a, b, c, 0, 0, 0);
}

// Async global->LDS, 16B per lane. LDS dest = wave-uniform base + lane*16.
__device__ __forceinline__ void gload16(const f16* g, f16* l) {
    __builtin_amdgcn_global_load_lds(
        (const __attribute__((address_space(1))) uint32_t*)g,
        (__attribute__((address_space(3))) uint32_t*)l, 16, 0, 0);
}

// ---------------------------------------------------------------------------
// GEMM v4 (256-class template): C[m][n] = (sum_k A[m*1024+k]*B[n*1024+k]
// + bias) * scale, K=1024. BM=256 x BN=128 x BK=64, 512 threads = 8 waves
// (4M x 2N, per-wave output 64x64). LDS = 2buf x (A 32KB + B 16KB) = 96KB
// -> 1 block/CU; overlap comes from the SCHEDULE, not cross-block TLP
// (the 128^2 attempts r1/r5 proved occupancy and depth trade 1:1 there).
// Per K-tile, two phases: {issue 3 stage loads for kt+1 -> ds_read 8 x b128
// -> setprio(1) 16 MFMA setprio(0) -> barrier}; ONE vmcnt(0) per K-tile at
// end-of-iter -- loads were issued a full compute phase earlier, so the
// drain is of old loads (issue-early / drain-late). Per wave per K-tile:
// 32 MFMA / 16 ds_read / 6 stages = 2x the compute-per-sync of 128^2.
// Swizzle carried over unchanged (proven 5 rounds): store side via
// pre-swizzled source chunk cg=(lane&7)^rg with linear gload_lds dest,
// read side cc=(ks*4+quad)^(l15&7) -> LDS[row][cc] holds global chunk
// ks*4+quad; 16-lane groups hit all 32 banks, 2-way max (free).
// ---------------------------------------------------------------------------
template <bool OUT16>
__device__ __forceinline__ void gemm256(const f16* __restrict__ A,
                                        const f16* __restrict__ B,
                                        const float* __restrict__ bias,
                                        void* __restrict__ Cout, long ldo,
                                        int biasrow, float scale,
                                        long m0, long n0, f16* As, f16* Bs) {
    int tid = threadIdx.x;
    int lane = tid & 63, w = tid >> 6;      // 8 waves
    int wm = w >> 1, wn = w & 1;            // 4 x 2 wave grid
    int l15 = lane & 15, quad = lane >> 4;
    int rg = lane >> 3, cg = (lane & 7) ^ rg;

    // staging bases: wave w covers rows p*64 + w*8 + rg of each 64-row part
    const f16* srcA = A + (m0 + w * 8 + rg) * 1024 + cg * 8;
    const f16* srcB = B + (n0 + w * 8 + rg) * 1024 + cg * 8;
    f16* dA = As + w * 512;  // + buf*16384 + p*4096
    f16* dB = Bs + w * 512;  // + buf*8192  + p*4096

    f32x4 acc[4][4] = {};

    // prologue: stage K-tile 0 into buf 0 (A parts 0..3, B parts 0..1)
#pragma unroll
    for (int p = 0; p < 4; ++p) gload16(srcA + p * 65536, dA + p * 4096);
#pragma unroll
    for (int p = 0; p < 2; ++p) gload16(srcB + p * 65536, dB + p * 4096);
    asm volatile("s_waitcnt vmcnt(0)" ::: "memory");
    __builtin_amdgcn_s_barrier();
    __builtin_amdgcn_sched_barrier(0);

    for (int kt = 0; kt < 16; ++kt) {
        int c = kt & 1;
        const f16* as = As + c * 16384;
        const f16* bs = Bs + c * 8192;
        f16* an = dA + (c ^ 1) * 16384;
        f16* bn = dB + (c ^ 1) * 8192;
        long ko = (long)(kt + 1) * 64;

        // ---- phase 0: stage A0,A1,B0 of kt+1; compute ks=0 ----
        if (kt < 15) {
            gload16(srcA + ko, an);
            gload16(srcA + 65536 + ko, an + 4096);
            gload16(srcB + ko, bn);
        }
        {
            int cc8 = (quad ^ (l15 & 7)) * 8;  // ks=0 chunk
            f16x8 af[4], bf[4];
#pragma unroll
            for (int t = 0; t < 4; ++t) {
                af[t] = *(const f16x8*)&as[(wm * 64 + t * 16 + l15) * 64 + cc8];
                bf[t] = *(const f16x8*)&bs[(wn * 64 + t * 16 + l15) * 64 + cc8];
            }
            __builtin_amdgcn_s_setprio(1);
#pragma unroll
            for (int i = 0; i < 4; ++i)
#pragma unroll
                for (int j = 0; j < 4; ++j)
                    acc[i][j] = mfma16(af[i], bf[j], acc[i][j]);
            __builtin_amdgcn_s_setprio(0);
        }
        __builtin_amdgcn_s_barrier();  // phase alignment (no data hazard)

        // ---- phase 1: stage A2,A3,B1 of kt+1; compute ks=1 ----
        if (kt < 15) {
            gload16(srcA + 2 * 65536 + ko, an + 8192);
            gload16(srcA + 3 * 65536 + ko, an + 12288);
            gload16(srcB + 65536 + ko, bn + 4096);
        }
        {
            int cc8 = ((4 + quad) ^ (l15 & 7)) * 8;  // ks=1 chunk
            f16x8 af[4], bf[4];
#pragma unroll
            for (int t = 0; t < 4; ++t) {
                af[t] = *(const f16x8*)&as[(wm * 64 + t * 16 + l15) * 64 + cc8];
                bf[t] = *(const f16x8*)&bs[(wn * 64 + t * 16 + l15) * 64 + cc8];
            }
            __builtin_amdgcn_s_setprio(1);
#pragma unroll
            for (int i = 0; i < 4; ++i)
#pragma unroll
                for (int j = 0; j < 4; ++j)
                    acc[i][j] = mfma16(af[i], bf[j], acc[i][j]);
            __builtin_amdgcn_s_setprio(0);
        }
        // end-of-iter: kt+1's 6 loads (issued one compute-phase ago) must be
        // globally retired before next iter's ds_reads; buf c overwrite only
        // happens after this barrier (next iter ph0), so reads are safe.
        if (kt < 15) asm volatile("s_waitcnt vmcnt(0)" ::: "memory");
        __builtin_amdgcn_s_barrier();
        __builtin_amdgcn_sched_barrier(0);
    }

    // C/D layout: col = lane&15, row = quad*4 + reg
#pragma unroll
    for (int i = 0; i < 4; ++i) {
        int mrow = wm * 64 + i * 16 + quad * 4;
#pragma unroll
        for (int j = 0; j < 4; ++j) {
            int ncol = wn * 64 + j * 16 + l15;
            long gn = n0 + ncol;
#pragma unroll
            for (int r = 0; r < 4; ++r) {
                long gm = m0 + mrow + r;
                float v = (acc[i][j][r] + (biasrow ? bias[gm] : bias[gn])) * scale;
                if constexpr (OUT16)
                    ((f16*)Cout)[gm * ldo + gn] = (f16)v;
                else
                    ((float*)Cout)[gm * ldo + gn] = v;
            }
        }
    }
}

// Merged Q/K/V projection: grid (256, 3); y selects operand set.
// z=0: Qp = (q@Wq^T+bq)*log2e/32  (softmax scale folded -> attn uses exp2)
// z=1: Kp = k@Wk^T+bk
// z=2: Vt = (v@Wv^T+bv)^T  computed as Wv x v^T -> [e][tok], bias per row
// 768 blocks at 1 block/CU = exactly 3 full residency rounds, zero tail.
__global__ __launch_bounds__(512, 2) void qkv_proj(
    const f16* __restrict__ qh, const f16* __restrict__ kh,
    const f16* __restrict__ vh, const f16* __restrict__ Wh,
    const float* __restrict__ bq, const float* __restrict__ bk,
    const float* __restrict__ bv, f16* __restrict__ Qp, f16* __restrict__ Kp,
    f16* __restrict__ Vt) {
    __shared__ __align__(16) f16 As[2 * 256 * 64];
    __shared__ __align__(16) f16 Bs[2 * 128 * 64];
    int z = blockIdx.y;
    int flat = blockIdx.x;
    const f16* A;
    const f16* B;
    const float* bias;
    f16* C;
    long ldo;
    int biasrow;
    float scale;
    if (z == 0) {
        A = qh; B = Wh; bias = bq; C = Qp; ldo = 1024; biasrow = 0;
        scale = 0.0450842200277786f;  // log2(e)/32
    } else if (z == 1) {
        A = kh; B = Wh + 1048576; bias = bk; C = Kp; ldo = 1024; biasrow = 0;
        scale = 1.0f;
    } else {
        A = Wh + 2097152; B = vh; bias = bv; C = Vt; ldo = 8192; biasrow = 1;
        scale = 1.0f;
    }
    long m0, n0;
    if (z == 2) {
        m0 = (long)(flat & 3) * 256;   // embed dim: 4 x 256
        n0 = (long)(flat >> 2) * 128;  // tokens:   64 x 128
    } else {
        m0 = (long)(flat & 31) * 256;  // tokens: 32 x 256
        n0 = (long)(flat >> 5) * 128;  // embed:   8 x 128
    }
    gemm256<true>(A, B, bias, C, ldo, biasrow, scale, m0, n0, As, Bs);
}

// Output projection: out = Op@Wo^T + bo (fp32 out). 256 blocks = 1 round.
__global__ __launch_bounds__(512, 2) void o_proj(const f16* __restrict__ Op,
                                                 const f16* __restrict__ Wo,
                                                 const float* __restrict__ bo,
                                                 float* __restrict__ out) {
    __shared__ __align__(16) f16 As[2 * 256 * 64];
    __shared__ __align__(16) f16 Bs[2 * 128 * 64];
    int flat = blockIdx.x;
    long m0 = (long)(flat & 31) * 256;
    long n0 = (long)(flat >> 5) * 128;
    gemm256<false>(Op, Wo, bo, out, 1024, 0, 1.0f, m0, n0, As, Bs);
}

// ---------------------------------------------------------------------------
// Attention v7 (unchanged from round 5 -- proven 84.6us): 512 blocks,
// 256-row q-pair, K/V tiles shared by both q-tiles, K/V TRIPLE-buffered
// (80KB LDS), prefetch tile kt+2, s_waitcnt vmcnt(4) + raw s_barrier per kt
// (T4 counted: tile kt+1 retired, kt+2 stays in flight). vmcnt(0) only at
// kt=30. P ds_writes wave-private. K/V LDS-staged (r4: per-wave L2 reads
// quadrupled traffic, -50%).
// ---------------------------------------------------------------------------
__global__ __launch_bounds__(256, 2) void attn256(const f16* __restrict__ Qp,
                                                  const f16* __restrict__ Kp,
                                                  const f16* __restrict__ Vt,
                                                  f16* __restrict__ Op) {
    __shared__ __align__(16) f16 Ps0[128 * 64];
    __shared__ __align__(16) f16 Ps1[128 * 64];
    __shared__ __align__(16) f16 Ks[3][64 * 64];
    __shared__ __align__(16) f16 Vs[3][64 * 64];

    int tid = threadIdx.x;
    int lane = tid & 63, w = tid >> 6;
    int l15 = lane & 15, quad = lane >> 4;
    int b = blockIdx.x;
    int xcd = b & 7, slot = b >> 3;        // 64 slots per XCD
    int nh = xcd * 8 + (slot >> 3);        // 8 (n,h) per XCD
    int qp = slot & 7;                     // 8 q-pairs per (n,h)
    int nb = nh >> 4, h = nh & 15;
    long tok0 = (long)nb * 2048;
    long qrow0 = qp * 256;

    int rg = lane >> 3, cg = (lane & 7) ^ rg;

    // stage both Q tiles FIRST (oldest vmcnt entries; wave-private rows)
    const f16* qsrc0 = Qp + (tok0 + qrow0) * 1024 + h * 64;
    const f16* qsrc1 = qsrc0 + 128 * 1024;
#pragma unroll
    for (int t = 0; t < 4; ++t) {
        int rb = w * 32 + t * 8;
        gload16(qsrc0 + (rb + rg) * 1024 + cg * 8, &Ps0[rb * 64]);
        gload16(qsrc1 + (rb + rg) * 1024 + cg * 8, &Ps1[rb * 64]);
    }
    // K/V tiles 0 and 1
    const f16* kptr = Kp + (tok0 + w * 16 + rg) * 1024 + h * 64 + cg * 8;
    const f16* vptr = Vt + ((long)h * 64 + w * 16 + rg) * 8192 + tok0 + cg * 8;
    gload16(kptr, &Ks[0][(w * 16) * 64]);
    gload16(kptr + 8 * 1024, &Ks[0][(w * 16 + 8) * 64]);
    gload16(vptr, &Vs[0][(w * 16) * 64]);
    gload16(vptr + (long)8 * 8192, &Vs[0][(w * 16 + 8) * 64]);
    gload16(kptr + 65536, &Ks[1][(w * 16) * 64]);
    gload16(kptr + 65536 + 8 * 1024, &Ks[1][(w * 16 + 8) * 64]);
    gload16(vptr + 64, &Vs[1][(w * 16) * 64]);
    gload16(vptr + 64 + (long)8 * 8192, &Vs[1][(w * 16 + 8) * 64]);
    const f16* kn = kptr + 2 * 65536;
    const f16* vn = vptr + 2 * 64;

    // hoist Q fragments: own-wave Q loads are the 8 oldest -> vmcnt(8);
    // rows are wave-private so no barrier needed before the reads
    asm volatile("s_waitcnt vmcnt(8)" ::: "memory");
    f16x8 qf0[2][2], qf1[2][2];
#pragma unroll
    for (int ks = 0; ks < 2; ++ks) {
        int cc = (ks * 4 + quad) ^ (l15 & 7);
#pragma unroll
        for (int j = 0; j < 2; ++j) {
            qf0[ks][j] = *(const f16x8*)&Ps0[(w * 32 + j * 16 + l15) * 64 + cc * 8];
            qf1[ks][j] = *(const f16x8*)&Ps1[(w * 32 + j * 16 + l15) * 64 + cc * 8];
        }
    }
    // K/V tile0 complete (cross-wave), tile1 left in flight
    asm volatile("s_waitcnt vmcnt(4)" ::: "memory");
    __builtin_amdgcn_s_barrier();
    __builtin_amdgcn_sched_barrier(0);

    f32x4 oacc0[2][4] = {}, oacc1[2][4] = {};
    float rs0[2] = {0.f, 0.f}, rs1[2] = {0.f, 0.f};
    const f32x4 z4 = {0.f, 0.f, 0.f, 0.f};

    int cur = 0;
    for (int kt = 0; kt < 32; ++kt) {
        // S tiles: K fragments read ONCE, feed both q-tiles
        f32x4 sacc0[4][2], sacc1[4][2];
        __builtin_amdgcn_s_setprio(1);
#pragma unroll
        for (int ks = 0; ks < 2; ++ks) {
            int cc = (ks * 4 + quad) ^ (l15 & 7);
            f16x8 a[4];
#pragma unroll
            for (int t = 0; t < 4; ++t)
                a[t] = *(const f16x8*)&Ks[cur][(t * 16 + l15) * 64 + cc * 8];
#pragma unroll
            for (int i = 0; i < 4; ++i)
#pragma unroll
                for (int j = 0; j < 2; ++j) {
                    if (ks == 0) {
                        sacc0[i][j] = mfma16(a[i], qf0[0][j], z4);
                        sacc1[i][j] = mfma16(a[i], qf1[0][j], z4);
                    } else {
                        sacc0[i][j] = mfma16(a[i], qf0[1][j], sacc0[i][j]);
                        sacc1[i][j] = mfma16(a[i], qf1[1][j], sacc1[i][j]);
                    }
                }
        }
        __builtin_amdgcn_s_setprio(0);
        // async prefetch tile kt+2 into slot (cur+2)%3 (read-fenced last iter)
        if (kt < 30) {
            int nxt = (cur == 0) ? 2 : cur - 1;
            f16* kd = &Ks[nxt][(w * 16) * 64];
            f16* vd = &Vs[nxt][(w * 16) * 64];
            gload16(kn, kd);
            gload16(kn + 8 * 1024, kd + 8 * 64);
            gload16(vn, vd);
            gload16(vn + (long)8 * 8192, vd + 8 * 64);
            kn += 65536;
            vn += 64;
        }
        // exp + rowsum + pack for both tiles (wave-private rows)
#pragma unroll
        for (int i = 0; i < 4; ++i) {
#pragma unroll
            for (int j = 0; j < 2; ++j) {
                int qrow = w * 32 + j * 16 + l15;
                int kl = i * 16 + quad * 4;
                int c = kl >> 3;
                int off = qrow * 64 + ((c ^ (qrow & 7)) << 3) + (kl & 7);
                {
                    float p0 = __builtin_amdgcn_exp2f(sacc0[i][j][0]);
                    float p1 = __builtin_amdgcn_exp2f(sacc0[i][j][1]);
                    float p2 = __builtin_amdgcn_exp2f(sacc0[i][j][2]);
                    float p3 = __builtin_amdgcn_exp2f(sacc0[i][j][3]);
                    rs0[j] += (p0 + p1) + (p2 + p3);
                    f16x2 lo = __builtin_bit_cast(f16x2, __builtin_amdgcn_cvt_pkrtz(p0, p1));
                    f16x2 hi = __builtin_bit_cast(f16x2, __builtin_amdgcn_cvt_pkrtz(p2, p3));
                    f16x4 ph;
                    ph[0] = lo[0]; ph[1] = lo[1]; ph[2] = hi[0]; ph[3] = hi[1];
                    *(f16x4*)&Ps0[off] = ph;
                }
                {
                    float p0 = __builtin_amdgcn_exp2f(sacc1[i][j][0]);
                    float p1 = __builtin_amdgcn_exp2f(sacc1[i][j][1]);
                    float p2 = __builtin_amdgcn_exp2f(sacc1[i][j][2]);
                    float p3 = __builtin_amdgcn_exp2f(sacc1[i][j][3]);
                    rs1[j] += (p0 + p1) + (p2 + p3);
                    f16x2 lo = __builtin_bit_cast(f16x2, __builtin_amdgcn_cvt_pkrtz(p0, p1));
                    f16x2 hi = __builtin_bit_cast(f16x2, __builtin_amdgcn_cvt_pkrtz(p2, p3));
                    f16x4 ph;
                    ph[0] = lo[0]; ph[1] = lo[1]; ph[2] = hi[0]; ph[3] = hi[1];
                    *(f16x4*)&Ps1[off] = ph;
                }
            }
        }
        // PV: V fragments read ONCE, feed both q-tiles
        __builtin_amdgcn_s_setprio(1);
#pragma unroll
        for (int ks = 0; ks < 2; ++ks) {
            int cc = (ks * 4 + quad) ^ (l15 & 7);
            f16x8 bf[4];
#pragma unroll
            for (int j = 0; j < 4; ++j)
                bf[j] = *(const f16x8*)&Vs[cur][(j * 16 + l15) * 64 + cc * 8];
            f16x8 af0[2], af1[2];
#pragma unroll
            for (int i = 0; i < 2; ++i) {
                af0[i] = *(const f16x8*)&Ps0[(w * 32 + i * 16 + l15) * 64 + cc * 8];
                af1[i] = *(const f16x8*)&Ps1[(w * 32 + i * 16 + l15) * 64 + cc * 8];
            }
#pragma unroll
            for (int i = 0; i < 2; ++i)
#pragma unroll
                for (int j = 0; j < 4; ++j) {
                    oacc0[i][j] = mfma16(af0[i], bf[j], oacc0[i][j]);
                    oacc1[i][j] = mfma16(af1[i], bf[j], oacc1[i][j]);
                }
        }
        __builtin_amdgcn_s_setprio(0);
        // counted-vmcnt barrier: tile kt+1 retired, tile kt+2 stays in flight
        if (kt < 31) {
            if (kt < 30)
                asm volatile("s_waitcnt vmcnt(4)" ::: "memory");
            else
                asm volatile("s_waitcnt vmcnt(0)" ::: "memory");
            __builtin_amdgcn_s_barrier();
            __builtin_amdgcn_sched_barrier(0);
        }
        cur = (cur == 2) ? 0 : cur + 1;
    }

    // rowsum reduction across quads; lsi aliases Ks[0] (last read kt=30,
    // fenced by that barrier; writes/reads are wave-private rows)
    float* lsi = (float*)&Ks[0][0];  // 256 floats
#pragma unroll
    for (int j = 0; j < 2; ++j) {
        rs0[j] += __shfl_xor(rs0[j], 16, 64);
        rs0[j] += __shfl_xor(rs0[j], 32, 64);
        rs1[j] += __shfl_xor(rs1[j], 16, 64);
        rs1[j] += __shfl_xor(rs1[j], 32, 64);
    }
    if (lane < 16) {
        lsi[w * 32 + lane] = 1.0f / rs0[0];
        lsi[w * 32 + 16 + lane] = 1.0f / rs0[1];
        lsi[128 + w * 32 + lane] = 1.0f / rs1[0];
        lsi[128 + w * 32 + 16 + lane] = 1.0f / rs1[1];
    }

    long otok = tok0 + qrow0;
#pragma unroll
    for (int i = 0; i < 2; ++i) {
        int qrow = w * 32 + i * 16 + quad * 4;
#pragma unroll
        for (int j = 0; j < 4; ++j) {
            int d = j * 16 + l15;
#pragma unroll
            for (int r = 0; r < 4; ++r) {
                Op[(otok + qrow + r) * 1024 + h * 64 + d] =
                    (f16)(oacc0[i][j][r] * lsi[qrow + r]);
                Op[(otok + 128 + qrow + r) * 1024 + h * 64 + d] =
                    (f16)(oacc1[i][j][r] * lsi[128 + qrow + r]);
            }
        }
    }
}

// Fused fp32->fp16 conversion: q,k,v (8.4M elems each) + 4 weights (1M each).
__global__ void cvt_all(const float* __restrict__ q, const float* __restrict__ k,
                        const float* __restrict__ v, const float* __restrict__ w0,
                        const float* __restrict__ w1, const float* __restrict__ w2,
                        const float* __restrict__ w3, f16* __restrict__ qh,
                        f16* __restrict__ kh, f16* __restrict__ vh,
                        f16* __restrict__ wh) {
    long id = (long)blockIdx.x * 256 + threadIdx.x;  // 3,670,016 total
    const float* s;
    f16* d;
    long off;
    if (id < 3145728) {
        int which = (int)(id >> 20);
        off = (id & 1048575) * 8;
        s = which == 0 ? q : which == 1 ? k : v;
        d = which == 0 ? qh : which == 1 ? kh : vh;
    } else {
        long id2 = id - 3145728;
        int wi = (int)(id2 >> 17);
        off = (id2 & 131071) * 8;
        s = wi == 0 ? w0 : wi == 1 ? w1 : wi == 2 ? w2 : w3;
        d = wh + (long)wi * 1048576;
    }
    f32x4 a = *(const f32x4*)(s + off);
    f32x4 b = *(const f32x4*)(s + off + 4);
    f16x8 hv;
    hv[0] = (f16)a[0]; hv[1] = (f16)a[1]; hv[2] = (f16)a[2]; hv[3] = (f16)a[3];
    hv[4] = (f16)b[0]; hv[5] = (f16)b[1]; hv[6] = (f16)b[2]; hv[7] = (f16)b[3];
    *(f16x8*)(d + off) = hv;
}

extern "C" void kernel_launch(void* const* d_in, const int* in_sizes, int n_in,
                              void* d_out, int out_size, void* d_ws, size_t ws_size,
                              hipStream_t stream) {
    const float* q  = (const float*)d_in[0];
    const float* k  = (const float*)d_in[1];
    const float* v  = (const float*)d_in[2];
    // d_in[3] padding_mask, d_in[4] sequence_mask: no effect in reference
    const float* Wq = (const float*)d_in[5];
    const float* bq = (const float*)d_in[6];
    const float* Wk = (const float*)d_in[7];
    const float* bk = (const float*)d_in[8];
    const float* Wv = (const float*)d_in[9];
    const float* bv = (const float*)d_in[10];
    const float* Wo = (const float*)d_in[11];
    const float* bo = (const float*)d_in[12];

    // 120 MB workspace, race-free across the merged qkv launch:
    //   qh [  0, 16MB)   kh [ 16, 32MB)   vh [ 32, 48MB)   Wh [ 48, 56MB)
    //   Qp [ 56, 72MB)   Kp [ 72, 88MB)   Vt [ 88,104MB)   Op [104,120MB)
    char* ws = (char*)d_ws;
    f16* qh = (f16*)ws;
    f16* kh = (f16*)(ws + (16L << 20));
    f16* vh = (f16*)(ws + (32L << 20));
    f16* Wh = (f16*)(ws + (48L << 20));
    f16* Qp = (f16*)(ws + (56L << 20));
    f16* Kp = (f16*)(ws + (72L << 20));
    f16* Vt = (f16*)(ws + (88L << 20));
    f16* Op = (f16*)(ws + (104L << 20));

    cvt_all<<<14336, 256, 0, stream>>>(q, k, v, Wq, Wk, Wv, Wo, qh, kh, vh, Wh);

    qkv_proj<<<dim3(256, 3), 512, 0, stream>>>(qh, kh, vh, Wh, bq, bk, bv,
                                               Qp, Kp, Vt);

    attn256<<<512, 256, 0, stream>>>(Qp, Kp, Vt, Op);

    o_proj<<<256, 512, 0, stream>>>(Op, Wh + 3145728, bo, (float*)d_out);
}

// Round 7
// 358.790 us; speedup vs baseline: 1.0090x; 1.0090x over previous
//
#include <hip/hip_runtime.h>
#include <stdint.h>

typedef _Float16 f16;
typedef _Float16 f16x8 __attribute__((ext_vector_type(8)));
typedef _Float16 f16x4 __attribute__((ext_vector_type(4)));
typedef _Float16 f16x2 __attribute__((ext_vector_type(2)));
typedef float f32x4 __attribute__((ext_vector_type(4)));

__device__ __forceinline__ f32x4 mfma16(f16x8 a, f16x8 b, f32x4 c) {
    return __builtin_amdgcn_mfma_f32_16x16x32_f16(a, b, c, 0, 0, 0);
}

// Async global->LDS, 16B per lane. LDS dest = wave-uniform base + lane*16.
__device__ __forceinline__ void gload16(const f16* g, f16* l) {
    __builtin_amdgcn_global_load_lds(
        (const __attribute__((address_space(1))) uint32_t*)g,
        (__attribute__((address_space(3))) uint32_t*)l, 16, 0, 0);
}

// RN fp32x8 -> f16x8 (same rounding as the old cvt_all kernel: scalar casts)
__device__ __forceinline__ f16x8 cvt8(f32x4 a, f32x4 b) {
    f16x8 h;
    h[0] = (f16)a[0]; h[1] = (f16)a[1]; h[2] = (f16)a[2]; h[3] = (f16)a[3];
    h[4] = (f16)b[0]; h[5] = (f16)b[1]; h[6] = (f16)b[2]; h[7] = (f16)b[3];
    return h;
}

// ---------------------------------------------------------------------------
// Fused-convert GEMM: C[m][n] = (sum_k A[m][k]*B[n][k] + bias) * scale,
// K=1024, 128x128 tile, 4 waves 2x2, BK=32, 32 K-iters (round-5's proven
// geometry -- its qkv measured <84us, beating the round-6 256-tile's 94).
//
// ROUND-7 CHANGE: the fp32->f16 conversion kernel (cvt_all, ~30us + launch
// gap) is FUSED into staging. B is always read as fp32 and reg-staged:
// load 2 x dwordx4 fp32 -> 8 RN (f16) casts -> 1 ds_write_b128. A is fp32
// reg-staged for qkv (A16=false) or f16 via gload16 for o_proj (A16=true,
// Op comes from attn as f16). Loads for tile kt+1 issue at iter START,
// cvt+ds_write happen AFTER the MFMA block (issue-early/write-late; the
// compiler auto-inserts vmcnt waits for the register loads). Double-buffer,
// one lgkmcnt(0)+s_barrier per iter. Totals ~230us of kernels sit under
// ~100us of fixed per-iteration harness overhead, so killing one launch is
// worth as much as a 30% kernel win.
//
// LDS layout is IDENTICAL to the proven gload16 swizzle:
//   LDS[row][c] = src[row][c ^ ((row>>1)&3)]   (row-major 128 x 32 f16)
// gload16 side realizes it via pre-swizzled source chunk
// c4=(lane&3)^((lane>>3)&3); reg-staged side writes src chunk g=lane&3 at
// stored position g^((r4>>1)&3). Read side (unchanged, 5 rounds proven):
// cs=(quad^((l15>>1)&3))*8 yields source chunk quad for every lane.
// ---------------------------------------------------------------------------
template <bool A16, bool OUT16>
__device__ __forceinline__ void gemm_fused(const void* __restrict__ Av,
                                           const float* __restrict__ B,
                                           const float* __restrict__ bias,
                                           void* __restrict__ Cout, long ldo,
                                           int biasrow, float scale,
                                           long m0, long n0, f16* As, f16* Bs) {
    int tid = threadIdx.x;
    int lane = tid & 63, w = tid >> 6;
    int wm = w & 1, wn = w >> 1;
    int l15 = lane & 15, quad = lane >> 4;

    int r4 = lane >> 2;                       // row within 16-row group
    int g = lane & 3;                         // source chunk (8 elems)
    int sc = g ^ ((r4 >> 1) & 3);             // stored chunk (reg-stage path)
    int c4 = (lane & 3) ^ ((lane >> 3) & 3);  // pre-swizzled src chunk (gload)

    const f16* a16 = (const f16*)Av;
    const float* a32 = (const float*)Av;

    // part t (t=0,1) covers rows t*64 + w*16 + [0,16)
    const f16* a16src[2];
    const float* a32src[2];
    const float* b32src[2];
    int lwoff[2];   // LDS part offset (f16 units), excl. slot
#pragma unroll
    for (int t = 0; t < 2; ++t) {
        long row = t * 64 + w * 16 + r4;
        if constexpr (A16)
            a16src[t] = a16 + (m0 + row) * 1024 + c4 * 8;
        else
            a32src[t] = a32 + (m0 + row) * 1024 + g * 8;
        b32src[t] = B + (n0 + row) * 1024 + g * 8;
        lwoff[t] = t * 2048 + w * 512;
    }
    int wroff = r4 * 32 + sc * 8;  // within-part write offset (reg-stage)

    f32x4 acc[4][4] = {};

    // ---- prologue: stage K-tile 0 into slot 0 ----
#pragma unroll
    for (int t = 0; t < 2; ++t) {
        if constexpr (A16) {
            gload16(a16src[t], As + lwoff[t]);
        } else {
            f32x4 x0 = *(const f32x4*)(a32src[t]);
            f32x4 x1 = *(const f32x4*)(a32src[t] + 4);
            *(f16x8*)&As[lwoff[t] + wroff] = cvt8(x0, x1);
        }
        f32x4 y0 = *(const f32x4*)(b32src[t]);
        f32x4 y1 = *(const f32x4*)(b32src[t] + 4);
        *(f16x8*)&Bs[lwoff[t] + wroff] = cvt8(y0, y1);
    }
    if constexpr (A16) asm volatile("s_waitcnt vmcnt(0)" ::: "memory");
    asm volatile("s_waitcnt lgkmcnt(0)" ::: "memory");
    __builtin_amdgcn_s_barrier();
    __builtin_amdgcn_sched_barrier(0);

    for (int kt = 0; kt < 32; ++kt) {
        int cur = kt & 1;
        int nxt = cur ^ 1;
        // ---- issue loads for tile kt+1 (consumed after the MFMA block) ----
        f32x4 la[2][2], lb[2][2];
        if (kt < 31) {
            long ko = (long)(kt + 1) * 32;
#pragma unroll
            for (int t = 0; t < 2; ++t) {
                if constexpr (A16) {
                    gload16(a16src[t] + ko, As + nxt * 4096 + lwoff[t]);
                } else {
                    la[t][0] = *(const f32x4*)(a32src[t] + ko);
                    la[t][1] = *(const f32x4*)(a32src[t] + ko + 4);
                }
                lb[t][0] = *(const f32x4*)(b32src[t] + ko);
                lb[t][1] = *(const f32x4*)(b32src[t] + ko + 4);
            }
        }
        // ---- compute tile kt from slot cur ----
        const f16* as = As + cur * 4096;
        const f16* bs = Bs + cur * 4096;
        int cs = (quad ^ ((l15 >> 1) & 3)) * 8;
        f16x8 af[4], bf[4];
#pragma unroll
        for (int t = 0; t < 4; ++t) {
            af[t] = *(const f16x8*)&as[(wm * 64 + t * 16 + l15) * 32 + cs];
            bf[t] = *(const f16x8*)&bs[(wn * 64 + t * 16 + l15) * 32 + cs];
        }
        __builtin_amdgcn_s_setprio(1);
#pragma unroll
        for (int i = 0; i < 4; ++i)
#pragma unroll
            for (int j = 0; j < 4; ++j)
                acc[i][j] = mfma16(af[i], bf[j], acc[i][j]);
        __builtin_amdgcn_s_setprio(0);
        // ---- convert + write staged tile kt+1 into slot nxt ----
        if (kt < 31) {
#pragma unroll
            for (int t = 0; t < 2; ++t) {
                if constexpr (!A16)
                    *(f16x8*)&As[nxt * 4096 + lwoff[t] + wroff] =
                        cvt8(la[t][0], la[t][1]);
                *(f16x8*)&Bs[nxt * 4096 + lwoff[t] + wroff] =
                    cvt8(lb[t][0], lb[t][1]);
            }
            if constexpr (A16) asm volatile("s_waitcnt vmcnt(0)" ::: "memory");
            asm volatile("s_waitcnt lgkmcnt(0)" ::: "memory");
            __builtin_amdgcn_s_barrier();
            __builtin_amdgcn_sched_barrier(0);
        }
    }

    // C/D layout: col = lane&15, row = quad*4 + reg
#pragma unroll
    for (int i = 0; i < 4; ++i) {
        int mrow = wm * 64 + i * 16 + quad * 4;
#pragma unroll
        for (int j = 0; j < 4; ++j) {
            int ncol = wn * 64 + j * 16 + l15;
            long gn = n0 + ncol;
#pragma unroll
            for (int r = 0; r < 4; ++r) {
                long gm = m0 + mrow + r;
                float v = (acc[i][j][r] + (biasrow ? bias[gm] : bias[gn])) * scale;
                if constexpr (OUT16)
                    ((f16*)Cout)[gm * ldo + gn] = (f16)v;
                else
                    ((float*)Cout)[gm * ldo + gn] = v;
            }
        }
    }
}

// Merged Q/K/V projection reading RAW fp32 inputs: grid (64, 8, 3).
// z=0: Qp = (q@Wq^T+bq)*log2e/32  (softmax scale folded -> attn uses exp2)
// z=1: Kp = k@Wk^T+bk
// z=2: Vt = (v@Wv^T+bv)^T  computed as Wv x v^T -> [e][tok], bias per row
__global__ __launch_bounds__(256, 2) void qkv_proj(
    const float* __restrict__ q, const float* __restrict__ k,
    const float* __restrict__ v, const float* __restrict__ Wq,
    const float* __restrict__ Wk, const float* __restrict__ Wv,
    const float* __restrict__ bq, const float* __restrict__ bk,
    const float* __restrict__ bv, f16* __restrict__ Qp, f16* __restrict__ Kp,
    f16* __restrict__ Vt) {
    __shared__ __align__(16) f16 As[2 * 4096];
    __shared__ __align__(16) f16 Bs[2 * 4096];
    int z = blockIdx.z;
    const float* A;
    const float* B;
    const float* bias;
    f16* C;
    long ldo;
    int biasrow;
    float scale;
    if (z == 0) {
        A = q; B = Wq; bias = bq; C = Qp; ldo = 1024; biasrow = 0;
        scale = 0.0450842200277786f;  // log2(e)/32
    } else if (z == 1) {
        A = k; B = Wk; bias = bk; C = Kp; ldo = 1024; biasrow = 0;
        scale = 1.0f;
    } else {
        A = Wv; B = v; bias = bv; C = Vt; ldo = 8192; biasrow = 1;
        scale = 1.0f;
    }
    long m0 = (long)(z == 2 ? blockIdx.y : blockIdx.x) * 128;
    long n0 = (long)(z == 2 ? blockIdx.x : blockIdx.y) * 128;
    gemm_fused<false, true>(A, B, bias, C, ldo, biasrow, scale, m0, n0, As, Bs);
}

// Output projection: out = Op@Wo^T + bo (fp32 out); A = Op f16 via gload16,
// B = Wo raw fp32 reg-staged.
__global__ __launch_bounds__(256, 2) void o_proj(const f16* __restrict__ Op,
                                                 const float* __restrict__ Wo,
                                                 const float* __restrict__ bo,
                                                 float* __restrict__ out) {
    __shared__ __align__(16) f16 As[2 * 4096];
    __shared__ __align__(16) f16 Bs[2 * 4096];
    gemm_fused<true, false>(Op, Wo, bo, out, 1024, 0, 1.0f,
                            (long)blockIdx.x * 128, (long)blockIdx.y * 128,
                            As, Bs);
}

// ---------------------------------------------------------------------------
// Attention v7 (unchanged -- proven 84.6us, counter-verified r5): 512 blocks,
// 256-row q-pair, K/V tiles shared by both q-tiles, K/V TRIPLE-buffered
// (80KB LDS), prefetch tile kt+2, s_waitcnt vmcnt(4) + raw s_barrier per kt
// (T4 counted: tile kt+1 retired, kt+2 stays in flight). vmcnt(0) only at
// kt=30. P ds_writes wave-private. K/V LDS-staged (r4: per-wave L2 reads
// quadrupled traffic, -50%).
// ---------------------------------------------------------------------------
__global__ __launch_bounds__(256, 2) void attn256(const f16* __restrict__ Qp,
                                                  const f16* __restrict__ Kp,
                                                  const f16* __restrict__ Vt,
                                                  f16* __restrict__ Op) {
    __shared__ __align__(16) f16 Ps0[128 * 64];
    __shared__ __align__(16) f16 Ps1[128 * 64];
    __shared__ __align__(16) f16 Ks[3][64 * 64];
    __shared__ __align__(16) f16 Vs[3][64 * 64];

    int tid = threadIdx.x;
    int lane = tid & 63, w = tid >> 6;
    int l15 = lane & 15, quad = lane >> 4;
    int b = blockIdx.x;
    int xcd = b & 7, slot = b >> 3;        // 64 slots per XCD
    int nh = xcd * 8 + (slot >> 3);        // 8 (n,h) per XCD
    int qp = slot & 7;                     // 8 q-pairs per (n,h)
    int nb = nh >> 4, h = nh & 15;
    long tok0 = (long)nb * 2048;
    long qrow0 = qp * 256;

    int rg = lane >> 3, cg = (lane & 7) ^ rg;

    // stage both Q tiles FIRST (oldest vmcnt entries; wave-private rows)
    const f16* qsrc0 = Qp + (tok0 + qrow0) * 1024 + h * 64;
    const f16* qsrc1 = qsrc0 + 128 * 1024;
#pragma unroll
    for (int t = 0; t < 4; ++t) {
        int rb = w * 32 + t * 8;
        gload16(qsrc0 + (rb + rg) * 1024 + cg * 8, &Ps0[rb * 64]);
        gload16(qsrc1 + (rb + rg) * 1024 + cg * 8, &Ps1[rb * 64]);
    }
    // K/V tiles 0 and 1
    const f16* kptr = Kp + (tok0 + w * 16 + rg) * 1024 + h * 64 + cg * 8;
    const f16* vptr = Vt + ((long)h * 64 + w * 16 + rg) * 8192 + tok0 + cg * 8;
    gload16(kptr, &Ks[0][(w * 16) * 64]);
    gload16(kptr + 8 * 1024, &Ks[0][(w * 16 + 8) * 64]);
    gload16(vptr, &Vs[0][(w * 16) * 64]);
    gload16(vptr + (long)8 * 8192, &Vs[0][(w * 16 + 8) * 64]);
    gload16(kptr + 65536, &Ks[1][(w * 16) * 64]);
    gload16(kptr + 65536 + 8 * 1024, &Ks[1][(w * 16 + 8) * 64]);
    gload16(vptr + 64, &Vs[1][(w * 16) * 64]);
    gload16(vptr + 64 + (long)8 * 8192, &Vs[1][(w * 16 + 8) * 64]);
    const f16* kn = kptr + 2 * 65536;
    const f16* vn = vptr + 2 * 64;

    // hoist Q fragments: own-wave Q loads are the 8 oldest -> vmcnt(8);
    // rows are wave-private so no barrier needed before the reads
    asm volatile("s_waitcnt vmcnt(8)" ::: "memory");
    f16x8 qf0[2][2], qf1[2][2];
#pragma unroll
    for (int ks = 0; ks < 2; ++ks) {
        int cc = (ks * 4 + quad) ^ (l15 & 7);
#pragma unroll
        for (int j = 0; j < 2; ++j) {
            qf0[ks][j] = *(const f16x8*)&Ps0[(w * 32 + j * 16 + l15) * 64 + cc * 8];
            qf1[ks][j] = *(const f16x8*)&Ps1[(w * 32 + j * 16 + l15) * 64 + cc * 8];
        }
    }
    // K/V tile0 complete (cross-wave), tile1 left in flight
    asm volatile("s_waitcnt vmcnt(4)" ::: "memory");
    __builtin_amdgcn_s_barrier();
    __builtin_amdgcn_sched_barrier(0);

    f32x4 oacc0[2][4] = {}, oacc1[2][4] = {};
    float rs0[2] = {0.f, 0.f}, rs1[2] = {0.f, 0.f};
    const f32x4 z4 = {0.f, 0.f, 0.f, 0.f};

    int cur = 0;
    for (int kt = 0; kt < 32; ++kt) {
        // S tiles: K fragments read ONCE, feed both q-tiles
        f32x4 sacc0[4][2], sacc1[4][2];
        __builtin_amdgcn_s_setprio(1);
#pragma unroll
        for (int ks = 0; ks < 2; ++ks) {
            int cc = (ks * 4 + quad) ^ (l15 & 7);
            f16x8 a[4];
#pragma unroll
            for (int t = 0; t < 4; ++t)
                a[t] = *(const f16x8*)&Ks[cur][(t * 16 + l15) * 64 + cc * 8];
#pragma unroll
            for (int i = 0; i < 4; ++i)
#pragma unroll
                for (int j = 0; j < 2; ++j) {
                    if (ks == 0) {
                        sacc0[i][j] = mfma16(a[i], qf0[0][j], z4);
                        sacc1[i][j] = mfma16(a[i], qf1[0][j], z4);
                    } else {
                        sacc0[i][j] = mfma16(a[i], qf0[1][j], sacc0[i][j]);
                        sacc1[i][j] = mfma16(a[i], qf1[1][j], sacc1[i][j]);
                    }
                }
        }
        __builtin_amdgcn_s_setprio(0);
        // async prefetch tile kt+2 into slot (cur+2)%3 (read-fenced last iter)
        if (kt < 30) {
            int nxt = (cur == 0) ? 2 : cur - 1;
            f16* kd = &Ks[nxt][(w * 16) * 64];
            f16* vd = &Vs[nxt][(w * 16) * 64];
            gload16(kn, kd);
            gload16(kn + 8 * 1024, kd + 8 * 64);
            gload16(vn, vd);
            gload16(vn + (long)8 * 8192, vd + 8 * 64);
            kn += 65536;
            vn += 64;
        }
        // exp + rowsum + pack for both tiles (wave-private rows)
#pragma unroll
        for (int i = 0; i < 4; ++i) {
#pragma unroll
            for (int j = 0; j < 2; ++j) {
                int qrow = w * 32 + j * 16 + l15;
                int kl = i * 16 + quad * 4;
                int c = kl >> 3;
                int off = qrow * 64 + ((c ^ (qrow & 7)) << 3) + (kl & 7);
                {
                    float p0 = __builtin_amdgcn_exp2f(sacc0[i][j][0]);
                    float p1 = __builtin_amdgcn_exp2f(sacc0[i][j][1]);
                    float p2 = __builtin_amdgcn_exp2f(sacc0[i][j][2]);
                    float p3 = __builtin_amdgcn_exp2f(sacc0[i][j][3]);
                    rs0[j] += (p0 + p1) + (p2 + p3);
                    f16x2 lo = __builtin_bit_cast(f16x2, __builtin_amdgcn_cvt_pkrtz(p0, p1));
                    f16x2 hi = __builtin_bit_cast(f16x2, __builtin_amdgcn_cvt_pkrtz(p2, p3));
                    f16x4 ph;
                    ph[0] = lo[0]; ph[1] = lo[1]; ph[2] = hi[0]; ph[3] = hi[1];
                    *(f16x4*)&Ps0[off] = ph;
                }
                {
                    float p0 = __builtin_amdgcn_exp2f(sacc1[i][j][0]);
                    float p1 = __builtin_amdgcn_exp2f(sacc1[i][j][1]);
                    float p2 = __builtin_amdgcn_exp2f(sacc1[i][j][2]);
                    float p3 = __builtin_amdgcn_exp2f(sacc1[i][j][3]);
                    rs1[j] += (p0 + p1) + (p2 + p3);
                    f16x2 lo = __builtin_bit_cast(f16x2, __builtin_amdgcn_cvt_pkrtz(p0, p1));
                    f16x2 hi = __builtin_bit_cast(f16x2, __builtin_amdgcn_cvt_pkrtz(p2, p3));
                    f16x4 ph;
                    ph[0] = lo[0]; ph[1] = lo[1]; ph[2] = hi[0]; ph[3] = hi[1];
                    *(f16x4*)&Ps1[off] = ph;
                }
            }
        }
        // PV: V fragments read ONCE, feed both q-tiles
        __builtin_amdgcn_s_setprio(1);
#pragma unroll
        for (int ks = 0; ks < 2; ++ks) {
            int cc = (ks * 4 + quad) ^ (l15 & 7);
            f16x8 bf[4];
#pragma unroll
            for (int j = 0; j < 4; ++j)
                bf[j] = *(const f16x8*)&Vs[cur][(j * 16 + l15) * 64 + cc * 8];
            f16x8 af0[2], af1[2];
#pragma unroll
            for (int i = 0; i < 2; ++i) {
                af0[i] = *(const f16x8*)&Ps0[(w * 32 + i * 16 + l15) * 64 + cc * 8];
                af1[i] = *(const f16x8*)&Ps1[(w * 32 + i * 16 + l15) * 64 + cc * 8];
            }
#pragma unroll
            for (int i = 0; i < 2; ++i)
#pragma unroll
                for (int j = 0; j < 4; ++j) {
                    oacc0[i][j] = mfma16(af0[i], bf[j], oacc0[i][j]);
                    oacc1[i][j] = mfma16(af1[i], bf[j], oacc1[i][j]);
                }
        }
        __builtin_amdgcn_s_setprio(0);
        // counted-vmcnt barrier: tile kt+1 retired, tile kt+2 stays in flight
        if (kt < 31) {
            if (kt < 30)
                asm volatile("s_waitcnt vmcnt(4)" ::: "memory");
            else
                asm volatile("s_waitcnt vmcnt(0)" ::: "memory");
            __builtin_amdgcn_s_barrier();
            __builtin_amdgcn_sched_barrier(0);
        }
        cur = (cur == 2) ? 0 : cur + 1;
    }

    // rowsum reduction across quads; lsi aliases Ks[0] (last read kt=30,
    // fenced by that barrier; writes/reads are wave-private rows)
    float* lsi = (float*)&Ks[0][0];  // 256 floats
#pragma unroll
    for (int j = 0; j < 2; ++j) {
        rs0[j] += __shfl_xor(rs0[j], 16, 64);
        rs0[j] += __shfl_xor(rs0[j], 32, 64);
        rs1[j] += __shfl_xor(rs1[j], 16, 64);
        rs1[j] += __shfl_xor(rs1[j], 32, 64);
    }
    if (lane < 16) {
        lsi[w * 32 + lane] = 1.0f / rs0[0];
        lsi[w * 32 + 16 + lane] = 1.0f / rs0[1];
        lsi[128 + w * 32 + lane] = 1.0f / rs1[0];
        lsi[128 + w * 32 + 16 + lane] = 1.0f / rs1[1];
    }

    long otok = tok0 + qrow0;
#pragma unroll
    for (int i = 0; i < 2; ++i) {
        int qrow = w * 32 + i * 16 + quad * 4;
#pragma unroll
        for (int j = 0; j < 4; ++j) {
            int d = j * 16 + l15;
#pragma unroll
            for (int r = 0; r < 4; ++r) {
                Op[(otok + qrow + r) * 1024 + h * 64 + d] =
                    (f16)(oacc0[i][j][r] * lsi[qrow + r]);
                Op[(otok + 128 + qrow + r) * 1024 + h * 64 + d] =
                    (f16)(oacc1[i][j][r] * lsi[128 + qrow + r]);
            }
        }
    }
}

extern "C" void kernel_launch(void* const* d_in, const int* in_sizes, int n_in,
                              void* d_out, int out_size, void* d_ws, size_t ws_size,
                              hipStream_t stream) {
    const float* q  = (const float*)d_in[0];
    const float* k  = (const float*)d_in[1];
    const float* v  = (const float*)d_in[2];
    // d_in[3] padding_mask, d_in[4] sequence_mask: no effect in reference
    const float* Wq = (const float*)d_in[5];
    const float* bq = (const float*)d_in[6];
    const float* Wk = (const float*)d_in[7];
    const float* bk = (const float*)d_in[8];
    const float* Wv = (const float*)d_in[9];
    const float* bv = (const float*)d_in[10];
    const float* Wo = (const float*)d_in[11];
    const float* bo = (const float*)d_in[12];

    // 64 MB workspace (fp32->f16 conversion now fused into the GEMMs):
    //   Qp [ 0, 16MB)   Kp [16, 32MB)   Vt [32, 48MB)   Op [48, 64MB)
    char* ws = (char*)d_ws;
    f16* Qp = (f16*)ws;
    f16* Kp = (f16*)(ws + (16L << 20));
    f16* Vt = (f16*)(ws + (32L << 20));
    f16* Op = (f16*)(ws + (48L << 20));

    qkv_proj<<<dim3(64, 8, 3), 256, 0, stream>>>(q, k, v, Wq, Wk, Wv,
                                                 bq, bk, bv, Qp, Kp, Vt);

    attn256<<<512, 256, 0, stream>>>(Qp, Kp, Vt, Op);

    o_proj<<<dim3(64, 8), 256, 0, stream>>>(Op, Wo, bo, (float*)d_out);
}